// Round 3
// baseline (290.467 us; speedup 1.0000x reference)
//
#include <hip/hip_runtime.h>
#include <stdint.h>

#define BB 4
#define CC 256
#define NN 16384  // 128*128

typedef unsigned short u16;
typedef __attribute__((ext_vector_type(8))) __bf16 bf16x8;
typedef __attribute__((ext_vector_type(4))) float f32x4;

// fp32 -> bf16 round-to-nearest-even
__device__ __forceinline__ u16 f2bf(float f) {
  union { float f; uint32_t u; } c;
  c.f = f;
  uint32_t u = c.u;
  return (u16)((u + 0x7fffu + ((u >> 16) & 1u)) >> 16);
}

// async global->LDS, 16 bytes per lane (global_load_lds_dwordx4)
__device__ __forceinline__ void g2l16(const u16* g, u16* l) {
  __builtin_amdgcn_global_load_lds((__attribute__((address_space(1))) void*)g,
                                   (__attribute__((address_space(3))) void*)l, 16, 0, 0);
}

// 256-thread block: stage 128x32 bf16 panel (row stride `stride`) into lds[128*32]
__device__ __forceinline__ void stage128x32(const u16* src, int stride, u16* lds, int tid) {
  int r = tid >> 2;
  int c = (tid & 3) << 3;
  g2l16(src + (size_t)r * stride + c, lds + r * 32 + c);
  g2l16(src + (size_t)(r + 64) * stride + c, lds + (r + 64) * 32 + c);
}

// 512-thread block: stage 128x32 panel (one g2l16/thread)
__device__ __forceinline__ void stage128x32_w8(const u16* src, int stride, u16* lds, int tid) {
  int r = tid >> 2;
  int c = (tid & 3) << 3;
  g2l16(src + (size_t)r * stride + c, lds + r * 32 + c);
}

// 512-thread block: stage 256x32 panel
__device__ __forceinline__ void stage256x32_w8(const u16* src, int stride, u16* lds, int tid) {
  int r = tid >> 2;
  int c = (tid & 3) << 3;
  g2l16(src + (size_t)r * stride + c, lds + r * 32 + c);
  g2l16(src + (size_t)(r + 128) * stride + c, lds + (r + 128) * 32 + c);
}

// one 32-deep k-step: 16 MFMAs on a 64x64 per-wave tile
__device__ __forceinline__ void mfma_tile(const u16* As, const u16* Bs, int mb, int nb,
                                          int l16, int q8, f32x4 acc[4][4]) {
  bf16x8 af[4], bf[4];
#pragma unroll
  for (int i = 0; i < 4; i++) af[i] = *(const bf16x8*)&As[(mb + i * 16 + l16) * 32 + q8];
#pragma unroll
  for (int i = 0; i < 4; i++) bf[i] = *(const bf16x8*)&Bs[(nb + i * 16 + l16) * 32 + q8];
#pragma unroll
  for (int i = 0; i < 4; i++)
#pragma unroll
    for (int j = 0; j < 4; j++)
      acc[i][j] = __builtin_amdgcn_mfma_f32_16x16x32_bf16(af[i], bf[j], acc[i][j], 0, 0, 0);
}

// prep: x fp32 (B,C,N) -> xb bf16 (B,C,N), xbT bf16 (B,N,C), s[b][c] = row sums
__global__ __launch_bounds__(256) void prep_kernel(const float* __restrict__ x,
                                                   u16* __restrict__ xb,
                                                   u16* __restrict__ xbT,
                                                   float* __restrict__ s) {
  __shared__ float t[64][65];
  __shared__ float rs[64][4];
  int n0 = blockIdx.x * 64, c0 = blockIdx.y * 64, bz = blockIdx.z;
  int tid = threadIdx.x;
  int rr0 = tid >> 4, q4 = (tid & 15) * 4;
  const float* xs = x + ((size_t)bz * CC + c0) * NN + n0;
  u16* xbp = xb + ((size_t)bz * CC + c0) * NN + n0;
#pragma unroll
  for (int cc = rr0; cc < 64; cc += 16) {
    float4 v = *(const float4*)&xs[(size_t)cc * NN + q4];
    t[cc][q4] = v.x; t[cc][q4 + 1] = v.y; t[cc][q4 + 2] = v.z; t[cc][q4 + 3] = v.w;
    union { u16 h[4]; uint2 u; } pk;
    pk.h[0] = f2bf(v.x); pk.h[1] = f2bf(v.y); pk.h[2] = f2bf(v.z); pk.h[3] = f2bf(v.w);
    *(uint2*)&xbp[(size_t)cc * NN + q4] = pk.u;
  }
  __syncthreads();
  {
    int r = tid >> 2, q = tid & 3;
    float p = 0.f;
#pragma unroll
    for (int i = 0; i < 16; i++) p += t[r][q * 16 + i];
    rs[r][q] = p;
  }
  u16* od = xbT + ((size_t)bz * NN + n0) * CC + c0;
#pragma unroll
  for (int nn = rr0; nn < 64; nn += 16) {
    union { u16 h[4]; uint2 u; } pk;
    pk.h[0] = f2bf(t[q4][nn]); pk.h[1] = f2bf(t[q4 + 1][nn]);
    pk.h[2] = f2bf(t[q4 + 2][nn]); pk.h[3] = f2bf(t[q4 + 3][nn]);
    *(uint2*)&od[(size_t)nn * CC + q4] = pk.u;
  }
  __syncthreads();
  if (tid < 64)
    atomicAdd(&s[bz * CC + c0 + tid], rs[tid][0] + rs[tid][1] + rs[tid][2] + rs[tid][3]);
}

// G[b] = xb[b] xb[b]^T  (C x C fp32, split-K=32 slices of 512, BK=64 via two panels)
__global__ __launch_bounds__(256) void gram_kernel(const u16* __restrict__ xb,
                                                   float* __restrict__ G) {
  __shared__ u16 As[2][128 * 32], Bs[2][128 * 32];
  int tid = threadIdx.x;
  int c0 = (blockIdx.x >> 1) * 128, d0 = (blockIdx.x & 1) * 128;
  int sl = blockIdx.y, bz = blockIdx.z;
  const u16* A = xb + ((size_t)bz * CC + c0) * NN + sl * 512;
  const u16* Bt = xb + ((size_t)bz * CC + d0) * NN + sl * 512;
  f32x4 acc[4][4] = {};
  int wave = tid >> 6, lane = tid & 63;
  int mb = (wave >> 1) * 64, nb = (wave & 1) * 64;
  int quad = lane >> 4, l16 = lane & 15, q8 = quad * 8;
  for (int kk = 0; kk < 512; kk += 64) {
    stage128x32(A + kk, NN, As[0], tid);
    stage128x32(A + kk + 32, NN, As[1], tid);
    stage128x32(Bt + kk, NN, Bs[0], tid);
    stage128x32(Bt + kk + 32, NN, Bs[1], tid);
    __syncthreads();
    mfma_tile(As[0], Bs[0], mb, nb, l16, q8, acc);
    mfma_tile(As[1], Bs[1], mb, nb, l16, q8, acc);
    __syncthreads();
  }
  float* g = G + (size_t)bz * CC * CC;
#pragma unroll
  for (int i = 0; i < 4; i++)
#pragma unroll
    for (int j = 0; j < 4; j++)
#pragma unroll
      for (int r = 0; r < 4; r++)
        atomicAdd(&g[(size_t)(c0 + mb + i * 16 + quad * 4 + r) * CC + d0 + nb + j * 16 + l16],
                  acc[i][j][r]);
}

// T[b][p][c] = sum_d Wk[p][d] G[b][d][c]   (fp32 NN GEMM, 32x32 tiles)
__global__ __launch_bounds__(256) void nn_T_kernel(const float* __restrict__ Wk,
                                                   const float* __restrict__ G,
                                                   float* __restrict__ T) {
  __shared__ float As[32][33], Bs2[32][33];
  int t = threadIdx.x;
  int c0 = blockIdx.x * 32, p0 = blockIdx.y * 32, b = blockIdx.z;
  const float* Ap = Wk + (size_t)p0 * CC;
  const float* Bp = G + (size_t)b * CC * CC + c0;
  float acc[2][2] = {};
  int r = t >> 3, c4 = (t & 7) * 4;
  int tr = t >> 4, tc = t & 15;
  for (int kk = 0; kk < CC; kk += 32) {
    float4 av = *(const float4*)&Ap[(size_t)r * CC + kk + c4];
    float4 bv = *(const float4*)&Bp[(size_t)(kk + r) * CC + c4];
    As[r][c4] = av.x; As[r][c4 + 1] = av.y; As[r][c4 + 2] = av.z; As[r][c4 + 3] = av.w;
    Bs2[r][c4] = bv.x; Bs2[r][c4 + 1] = bv.y; Bs2[r][c4 + 2] = bv.z; Bs2[r][c4 + 3] = bv.w;
    __syncthreads();
#pragma unroll
    for (int k = 0; k < 32; k++) {
      float a0 = As[tr * 2][k], a1 = As[tr * 2 + 1][k];
      float b0 = Bs2[k][tc * 2], b1 = Bs2[k][tc * 2 + 1];
      acc[0][0] += a0 * b0; acc[0][1] += a0 * b1;
      acc[1][0] += a1 * b0; acc[1][1] += a1 * b1;
    }
    __syncthreads();
  }
#pragma unroll
  for (int i = 0; i < 2; i++)
#pragma unroll
    for (int j = 0; j < 2; j++)
      T[(size_t)b * CC * CC + (size_t)(p0 + tr * 2 + i) * CC + c0 + tc * 2 + j] = acc[i][j];
}

// epi: u,w + E = Wq T^T (+rank-1) /128 + row softmax + att + bo, all in one kernel.
// grid (8 o-tiles, B), 256 threads; each block owns 32 o-rows x all 256 p.
__global__ __launch_bounds__(256) void epi_kernel(
    const float* __restrict__ Wq, const float* __restrict__ Wk,
    const float* __restrict__ T, const float* __restrict__ s,
    const float* __restrict__ bq, const float* __restrict__ bk,
    const float* __restrict__ bv,
    float* __restrict__ att, float* __restrict__ bo) {
  __shared__ float sS[CC], wS[CC], bkS[CC], bvS[CC], uS[32];
  __shared__ float WqS[32][257];
  __shared__ float TS[32][257];
  __shared__ float ES[32][257];
  __shared__ float red[32][8];
  int t = threadIdx.x;
  int o0 = blockIdx.x * 32, b = blockIdx.y;
  sS[t] = s[b * CC + t];
  bkS[t] = bk[t];
  bvS[t] = bv[t];
#pragma unroll
  for (int j = 0; j < 8; j++) {
    int e4 = t + j * 256;
    int row = e4 >> 6, col = (e4 & 63) << 2;
    float4 v = *(const float4*)&Wq[(size_t)(o0 + row) * CC + col];
    WqS[row][col] = v.x; WqS[row][col + 1] = v.y;
    WqS[row][col + 2] = v.z; WqS[row][col + 3] = v.w;
  }
  __syncthreads();
  {
    const float4* row = (const float4*)&Wk[(size_t)t * CC];
    float a = 0.f;
#pragma unroll 4
    for (int c = 0; c < 64; c++) {
      float4 v = row[c];
      a += v.x * sS[c * 4] + v.y * sS[c * 4 + 1] + v.z * sS[c * 4 + 2] + v.w * sS[c * 4 + 3];
    }
    wS[t] = a;
  }
  if (t < 32) {
    float a = 0.f;
    for (int c = 0; c < CC; c++) a += WqS[t][c] * sS[c];
    uS[t] = a;
  }
  int ol = t >> 3, pq = t & 7, pl = pq * 4;
  for (int pt = 0; pt < 8; pt++) {
#pragma unroll
    for (int j = 0; j < 8; j++) {
      int e4 = t + j * 256;
      int row = e4 >> 6, col = (e4 & 63) << 2;
      float4 v = *(const float4*)&T[(size_t)b * CC * CC + (size_t)(pt * 32 + row) * CC + col];
      TS[row][col] = v.x; TS[row][col + 1] = v.y;
      TS[row][col + 2] = v.z; TS[row][col + 3] = v.w;
    }
    __syncthreads();
    float a0 = 0, a1 = 0, a2 = 0, a3 = 0;
#pragma unroll 8
    for (int c = 0; c < CC; c++) {
      float a = WqS[ol][c];
      a0 += a * TS[pl + 0][c];
      a1 += a * TS[pl + 1][c];
      a2 += a * TS[pl + 2][c];
      a3 += a * TS[pl + 3][c];
    }
    ES[ol][pt * 32 + pl + 0] = a0;
    ES[ol][pt * 32 + pl + 1] = a1;
    ES[ol][pt * 32 + pl + 2] = a2;
    ES[ol][pt * 32 + pl + 3] = a3;
    __syncthreads();
  }
  float bqo = bq[o0 + ol];
  float um = uS[ol];
  float ev[32];
  float lmax = -1e30f;
#pragma unroll
  for (int i = 0; i < 32; i++) {
    int p = pq + 8 * i;
    float e = (ES[ol][p] + um * bkS[p] + bqo * wS[p] + 16384.f * bqo * bkS[p]) * 0.0078125f;
    ev[i] = e;
    lmax = fmaxf(lmax, e);
  }
  red[ol][pq] = lmax;
  __syncthreads();
  float m = red[ol][0];
#pragma unroll
  for (int j = 1; j < 8; j++) m = fmaxf(m, red[ol][j]);
  __syncthreads();
  float lsum = 0.f;
#pragma unroll
  for (int i = 0; i < 32; i++) {
    ev[i] = __expf(ev[i] - m);
    lsum += ev[i];
  }
  red[ol][pq] = lsum;
  __syncthreads();
  float sum = 0.f;
#pragma unroll
  for (int j = 0; j < 8; j++) sum += red[ol][j];
  float inv = 1.f / sum;
  float lbo = 0.f;
  float* ar = att + ((size_t)b * CC + o0 + ol) * CC;
#pragma unroll
  for (int i = 0; i < 32; i++) {
    int p = pq + 8 * i;
    float a = ev[i] * inv;
    ar[p] = a;
    lbo += a * bvS[p];
  }
  __syncthreads();
  red[ol][pq] = lbo;
  __syncthreads();
  if (pq == 0) {
    float bb = 0.f;
#pragma unroll
    for (int j = 0; j < 8; j++) bb += red[ol][j];
    bo[b * CC + o0 + ol] = bb;
  }
}

// Mv[b][o][c'] = sum_d att[b][o][d] Wv[d][c']  -> bf16
__global__ __launch_bounds__(256) void nn_Mv_kernel(const float* __restrict__ att,
                                                    const float* __restrict__ Wv,
                                                    u16* __restrict__ Mvb) {
  __shared__ float As[32][33], Bs2[32][33];
  int t = threadIdx.x;
  int c0 = blockIdx.x * 32, o0 = blockIdx.y * 32, b = blockIdx.z;
  const float* Ap = att + (size_t)b * CC * CC + (size_t)o0 * CC;
  const float* Bp = Wv + c0;
  float acc[2][2] = {};
  int r = t >> 3, c4 = (t & 7) * 4;
  int tr = t >> 4, tc = t & 15;
  for (int kk = 0; kk < CC; kk += 32) {
    float4 av = *(const float4*)&Ap[(size_t)r * CC + kk + c4];
    float4 bv = *(const float4*)&Bp[(size_t)(kk + r) * CC + c4];
    As[r][c4] = av.x; As[r][c4 + 1] = av.y; As[r][c4 + 2] = av.z; As[r][c4 + 3] = av.w;
    Bs2[r][c4] = bv.x; Bs2[r][c4 + 1] = bv.y; Bs2[r][c4 + 2] = bv.z; Bs2[r][c4 + 3] = bv.w;
    __syncthreads();
#pragma unroll
    for (int k = 0; k < 32; k++) {
      float a0 = As[tr * 2][k], a1 = As[tr * 2 + 1][k];
      float b0 = Bs2[k][tc * 2], b1 = Bs2[k][tc * 2 + 1];
      acc[0][0] += a0 * b0; acc[0][1] += a0 * b1;
      acc[1][0] += a1 * b0; acc[1][1] += a1 * b1;
    }
    __syncthreads();
  }
#pragma unroll
  for (int i = 0; i < 2; i++)
#pragma unroll
    for (int j = 0; j < 2; j++)
      Mvb[(size_t)b * CC * CC + (size_t)(o0 + tr * 2 + i) * CC + c0 + tc * 2 + j] =
          f2bf(acc[i][j]);
}

// out[b][c][n] = sum_c' Mv[c][c'] x[c'][n] + bo[c] + x[c][n]
// 512-thread blocks, 128(c) x 256(n) tile, BK=64 via two 32-panels
__global__ __launch_bounds__(512) void out_kernel(const u16* __restrict__ Mvb,
                                                  const u16* __restrict__ xbT,
                                                  const float* __restrict__ bo,
                                                  const float* __restrict__ x,
                                                  float* __restrict__ out) {
  __shared__ u16 As[2][128 * 32], Bs[2][256 * 32];
  int tid = threadIdx.x;
  int n0 = blockIdx.x * 256, m0 = blockIdx.y * 128, bz = blockIdx.z;
  const u16* A = Mvb + (size_t)bz * CC * CC + (size_t)m0 * CC;
  const u16* Bt = xbT + ((size_t)bz * NN + n0) * CC;
  f32x4 acc[4][4] = {};
  int wave = tid >> 6, lane = tid & 63;
  int mb = (wave & 1) * 64, nb = (wave >> 1) * 64;
  int quad = lane >> 4, l16 = lane & 15, q8 = quad * 8;
  for (int kk = 0; kk < CC; kk += 64) {
    stage128x32_w8(A + kk, CC, As[0], tid);
    stage128x32_w8(A + kk + 32, CC, As[1], tid);
    stage256x32_w8(Bt + kk, CC, Bs[0], tid);
    stage256x32_w8(Bt + kk + 32, CC, Bs[1], tid);
    __syncthreads();
    mfma_tile(As[0], Bs[0], mb, nb, l16, q8, acc);
    mfma_tile(As[1], Bs[1], mb, nb, l16, q8, acc);
    __syncthreads();
  }
#pragma unroll
  for (int i = 0; i < 4; i++)
#pragma unroll
    for (int r = 0; r < 4; r++) {
      int cg = m0 + mb + i * 16 + quad * 4 + r;
      float bc = bo[bz * CC + cg];
#pragma unroll
      for (int j = 0; j < 4; j++) {
        int ng = n0 + nb + j * 16 + l16;
        size_t idx = ((size_t)bz * CC + cg) * NN + ng;
        out[idx] = acc[i][j][r] + bc + x[idx];
      }
    }
}

extern "C" void kernel_launch(void* const* d_in, const int* in_sizes, int n_in,
                              void* d_out, int out_size, void* d_ws, size_t ws_size,
                              hipStream_t stream) {
  (void)in_sizes; (void)n_in; (void)out_size; (void)ws_size;
  const float* x = (const float*)d_in[0];
  const float* wq = (const float*)d_in[1];
  const float* bq = (const float*)d_in[2];
  const float* wk = (const float*)d_in[3];
  const float* bk = (const float*)d_in[4];
  const float* wv = (const float*)d_in[5];
  const float* bv = (const float*)d_in[6];
  float* out = (float*)d_out;

  char* ws = (char*)d_ws;
  u16* xb    = (u16*)(ws + 0);           // 32 MiB  (B,C,N) bf16
  u16* xbT   = (u16*)(ws + 33554432);    // 32 MiB  (B,N,C) bf16
  float* G   = (float*)(ws + 67108864);  // 1 MiB   (B,C,C) fp32
  float* s   = (float*)(ws + 68157440);  // 4 KiB   (B,C)   (adjacent to G: one memset)
  float* T   = (float*)(ws + 68161536);  // 1 MiB
  float* att = (float*)(ws + 69210112);  // 1 MiB
  u16* Mvb   = (u16*)(ws + 70258688);    // 512 KiB
  float* bo  = (float*)(ws + 70782976);  // 4 KiB

  hipMemsetAsync(G, 0, 1048576 + 4096, stream);
  prep_kernel<<<dim3(NN / 64, CC / 64, BB), 256, 0, stream>>>(x, xb, xbT, s);
  gram_kernel<<<dim3(4, 32, BB), 256, 0, stream>>>(xb, G);
  nn_T_kernel<<<dim3(8, 8, BB), 256, 0, stream>>>(wk, G, T);
  epi_kernel<<<dim3(8, BB), 256, 0, stream>>>(wq, wk, T, s, bq, bk, bv, att, bo);
  nn_Mv_kernel<<<dim3(8, 8, BB), 256, 0, stream>>>(att, wv, Mvb);
  out_kernel<<<dim3(NN / 256, CC / 128, BB), 512, 0, stream>>>(Mvb, xbT, bo, x, out);
}

// Round 4
// 247.485 us; speedup vs baseline: 1.1737x; 1.1737x over previous
//
#include <hip/hip_runtime.h>
#include <stdint.h>

#define BB 4
#define CC 256
#define NN 16384  // 128*128

typedef unsigned short u16;
typedef __attribute__((ext_vector_type(8))) __bf16 bf16x8;
typedef __attribute__((ext_vector_type(4))) float f32x4;

// fp32 -> bf16 round-to-nearest-even
__device__ __forceinline__ u16 f2bf(float f) {
  union { float f; uint32_t u; } c;
  c.f = f;
  uint32_t u = c.u;
  return (u16)((u + 0x7fffu + ((u >> 16) & 1u)) >> 16);
}

// async global->LDS, 16 bytes per lane (global_load_lds_dwordx4)
__device__ __forceinline__ void g2l16(const u16* g, u16* l) {
  __builtin_amdgcn_global_load_lds((__attribute__((address_space(1))) void*)g,
                                   (__attribute__((address_space(3))) void*)l, 16, 0, 0);
}

// 256-thread block: stage 128x32 bf16 panel (row stride `stride`) into lds[128*32]
__device__ __forceinline__ void stage128x32(const u16* src, int stride, u16* lds, int tid) {
  int r = tid >> 2;
  int c = (tid & 3) << 3;
  g2l16(src + (size_t)r * stride + c, lds + r * 32 + c);
  g2l16(src + (size_t)(r + 64) * stride + c, lds + (r + 64) * 32 + c);
}

// 512-thread block: stage 128x32 panel (one g2l16/thread)
__device__ __forceinline__ void stage128x32_w8(const u16* src, int stride, u16* lds, int tid) {
  int r = tid >> 2;
  int c = (tid & 3) << 3;
  g2l16(src + (size_t)r * stride + c, lds + r * 32 + c);
}

// 512-thread block: stage 256x32 panel
__device__ __forceinline__ void stage256x32_w8(const u16* src, int stride, u16* lds, int tid) {
  int r = tid >> 2;
  int c = (tid & 3) << 3;
  g2l16(src + (size_t)r * stride + c, lds + r * 32 + c);
  g2l16(src + (size_t)(r + 128) * stride + c, lds + (r + 128) * 32 + c);
}

// one 32-deep k-step: 16 MFMAs on a 64x64 per-wave tile
__device__ __forceinline__ void mfma_tile(const u16* As, const u16* Bs, int mb, int nb,
                                          int l16, int q8, f32x4 acc[4][4]) {
  bf16x8 af[4], bf[4];
#pragma unroll
  for (int i = 0; i < 4; i++) af[i] = *(const bf16x8*)&As[(mb + i * 16 + l16) * 32 + q8];
#pragma unroll
  for (int i = 0; i < 4; i++) bf[i] = *(const bf16x8*)&Bs[(nb + i * 16 + l16) * 32 + q8];
#pragma unroll
  for (int i = 0; i < 4; i++)
#pragma unroll
    for (int j = 0; j < 4; j++)
      acc[i][j] = __builtin_amdgcn_mfma_f32_16x16x32_bf16(af[i], bf[j], acc[i][j], 0, 0, 0);
}

// prep: x fp32 (B,C,N) -> xb bf16 (B,C,N), xbT bf16 (B,N,C), s[b][c] = row sums
__global__ __launch_bounds__(256) void prep_kernel(const float* __restrict__ x,
                                                   u16* __restrict__ xb,
                                                   u16* __restrict__ xbT,
                                                   float* __restrict__ s) {
  __shared__ float t[64][65];
  __shared__ float rs[64][4];
  int n0 = blockIdx.x * 64, c0 = blockIdx.y * 64, bz = blockIdx.z;
  int tid = threadIdx.x;
  int rr0 = tid >> 4, q4 = (tid & 15) * 4;
  const float* xs = x + ((size_t)bz * CC + c0) * NN + n0;
  u16* xbp = xb + ((size_t)bz * CC + c0) * NN + n0;
#pragma unroll
  for (int cc = rr0; cc < 64; cc += 16) {
    float4 v = *(const float4*)&xs[(size_t)cc * NN + q4];
    t[cc][q4] = v.x; t[cc][q4 + 1] = v.y; t[cc][q4 + 2] = v.z; t[cc][q4 + 3] = v.w;
    union { u16 h[4]; uint2 u; } pk;
    pk.h[0] = f2bf(v.x); pk.h[1] = f2bf(v.y); pk.h[2] = f2bf(v.z); pk.h[3] = f2bf(v.w);
    *(uint2*)&xbp[(size_t)cc * NN + q4] = pk.u;
  }
  __syncthreads();
  {
    int r = tid >> 2, q = tid & 3;
    float p = 0.f;
#pragma unroll
    for (int i = 0; i < 16; i++) p += t[r][q * 16 + i];
    rs[r][q] = p;
  }
  u16* od = xbT + ((size_t)bz * NN + n0) * CC + c0;
#pragma unroll
  for (int nn = rr0; nn < 64; nn += 16) {
    union { u16 h[4]; uint2 u; } pk;
    pk.h[0] = f2bf(t[q4][nn]); pk.h[1] = f2bf(t[q4 + 1][nn]);
    pk.h[2] = f2bf(t[q4 + 2][nn]); pk.h[3] = f2bf(t[q4 + 3][nn]);
    *(uint2*)&od[(size_t)nn * CC + q4] = pk.u;
  }
  __syncthreads();
  if (tid < 64)
    atomicAdd(&s[bz * CC + c0 + tid], rs[tid][0] + rs[tid][1] + rs[tid][2] + rs[tid][3]);
}

// G[b] = xb[b] xb[b]^T  (C x C fp32, split-K=32 slices of 512, BK=64 via two panels)
__global__ __launch_bounds__(256) void gram_kernel(const u16* __restrict__ xb,
                                                   float* __restrict__ G) {
  __shared__ u16 As[2][128 * 32], Bs[2][128 * 32];
  int tid = threadIdx.x;
  int c0 = (blockIdx.x >> 1) * 128, d0 = (blockIdx.x & 1) * 128;
  int sl = blockIdx.y, bz = blockIdx.z;
  const u16* A = xb + ((size_t)bz * CC + c0) * NN + sl * 512;
  const u16* Bt = xb + ((size_t)bz * CC + d0) * NN + sl * 512;
  f32x4 acc[4][4] = {};
  int wave = tid >> 6, lane = tid & 63;
  int mb = (wave >> 1) * 64, nb = (wave & 1) * 64;
  int quad = lane >> 4, l16 = lane & 15, q8 = quad * 8;
  for (int kk = 0; kk < 512; kk += 64) {
    stage128x32(A + kk, NN, As[0], tid);
    stage128x32(A + kk + 32, NN, As[1], tid);
    stage128x32(Bt + kk, NN, Bs[0], tid);
    stage128x32(Bt + kk + 32, NN, Bs[1], tid);
    __syncthreads();
    mfma_tile(As[0], Bs[0], mb, nb, l16, q8, acc);
    mfma_tile(As[1], Bs[1], mb, nb, l16, q8, acc);
    __syncthreads();
  }
  float* g = G + (size_t)bz * CC * CC;
#pragma unroll
  for (int i = 0; i < 4; i++)
#pragma unroll
    for (int j = 0; j < 4; j++)
#pragma unroll
      for (int r = 0; r < 4; r++)
        atomicAdd(&g[(size_t)(c0 + mb + i * 16 + quad * 4 + r) * CC + d0 + nb + j * 16 + l16],
                  acc[i][j][r]);
}

// R[b][o][c] = sum_d Wq[o][d] G[b][d][c] + bq[o]*s[b][c]   (fp32 NN GEMM, 32x32 tiles)
__global__ __launch_bounds__(256) void ru_kernel(const float* __restrict__ Wq,
                                                 const float* __restrict__ G,
                                                 const float* __restrict__ s,
                                                 const float* __restrict__ bq,
                                                 float* __restrict__ R) {
  __shared__ float As[32][33], Bs2[32][33];
  int t = threadIdx.x;
  int c0 = blockIdx.x * 32, o0 = blockIdx.y * 32, b = blockIdx.z;
  const float* Ap = Wq + (size_t)o0 * CC;
  const float* Bp = G + (size_t)b * CC * CC + c0;
  float acc[2][2] = {};
  int r = t >> 3, c4 = (t & 7) * 4;
  int tr = t >> 4, tc = t & 15;
  for (int kk = 0; kk < CC; kk += 32) {
    float4 av = *(const float4*)&Ap[(size_t)r * CC + kk + c4];
    float4 bv = *(const float4*)&Bp[(size_t)(kk + r) * CC + c4];
    As[r][c4] = av.x; As[r][c4 + 1] = av.y; As[r][c4 + 2] = av.z; As[r][c4 + 3] = av.w;
    Bs2[r][c4] = bv.x; Bs2[r][c4 + 1] = bv.y; Bs2[r][c4 + 2] = bv.z; Bs2[r][c4 + 3] = bv.w;
    __syncthreads();
#pragma unroll
    for (int k = 0; k < 32; k++) {
      float a0 = As[tr * 2][k], a1 = As[tr * 2 + 1][k];
      float b0 = Bs2[k][tc * 2], b1 = Bs2[k][tc * 2 + 1];
      acc[0][0] += a0 * b0; acc[0][1] += a0 * b1;
      acc[1][0] += a1 * b0; acc[1][1] += a1 * b1;
    }
    __syncthreads();
  }
#pragma unroll
  for (int i = 0; i < 2; i++)
#pragma unroll
    for (int j = 0; j < 2; j++) {
      int o = o0 + tr * 2 + i, c = c0 + tc * 2 + j;
      R[(size_t)b * CC * CC + (size_t)o * CC + c] = acc[i][j] + bq[o] * s[b * CC + c];
    }
}

// esb: E = R Wk^T + u' (x) bk, scale 1/128, softmax over p, att + bo.
// grid (32 o-tiles of 8, B), 256 threads (thread = p). R rows are block-uniform.
__global__ __launch_bounds__(256) void esb_kernel(
    const float* __restrict__ R, const float* __restrict__ Wq,
    const float* __restrict__ Wk, const float* __restrict__ s,
    const float* __restrict__ bq, const float* __restrict__ bk,
    const float* __restrict__ bv,
    float* __restrict__ att, float* __restrict__ bo) {
  __shared__ float upS[8];
  __shared__ float red[4][8];
  __shared__ float red2[4][16];
  int t = threadIdx.x;
  int o0 = blockIdx.x * 8, b = blockIdx.y;
  // u'[o] = Wq[o,:].s[b] + N*bq[o]   (8 rows, 32 lanes each)
  {
    int o = t >> 5, l = t & 31;
    const float* wqr = Wq + (size_t)(o0 + o) * CC;
    const float* sb = s + b * CC;
    float p = 0.f;
#pragma unroll
    for (int k = 0; k < 8; k++) p += wqr[l + 32 * k] * sb[l + 32 * k];
#pragma unroll
    for (int d = 16; d > 0; d >>= 1) p += __shfl_xor(p, d, 32);
    if (l == 0) upS[o] = p + 16384.f * bq[o0 + o];
  }
  __syncthreads();
  float bkp = bk[t], bvp = bv[t];
  float acc[8];
#pragma unroll
  for (int o = 0; o < 8; o++) acc[o] = upS[o] * bkp;
  const float* wkr = Wk + (size_t)t * CC;
  const float* Rb = R + ((size_t)b * CC + o0) * CC;
  for (int c = 0; c < CC; c += 4) {
    float4 wv4 = *(const float4*)&wkr[c];
#pragma unroll
    for (int o = 0; o < 8; o++) {
      float4 rv = *(const float4*)&Rb[(size_t)o * CC + c];  // uniform -> s_load
      acc[o] += rv.x * wv4.x + rv.y * wv4.y + rv.z * wv4.z + rv.w * wv4.w;
    }
  }
#pragma unroll
  for (int o = 0; o < 8; o++) acc[o] *= 0.0078125f;
  int wv = t >> 6, ln = t & 63;
  // per-o max across 256 threads
#pragma unroll
  for (int o = 0; o < 8; o++) {
    float v = acc[o];
#pragma unroll
    for (int d = 32; d > 0; d >>= 1) v = fmaxf(v, __shfl_xor(v, d, 64));
    if (ln == 0) red[wv][o] = v;
  }
  __syncthreads();
  float m[8];
#pragma unroll
  for (int o = 0; o < 8; o++)
    m[o] = fmaxf(fmaxf(red[0][o], red[1][o]), fmaxf(red[2][o], red[3][o]));
#pragma unroll
  for (int o = 0; o < 8; o++) acc[o] = __expf(acc[o] - m[o]);
  // per-o sum + bo partial
#pragma unroll
  for (int o = 0; o < 8; o++) {
    float v = acc[o], w2 = acc[o] * bvp;
#pragma unroll
    for (int d = 32; d > 0; d >>= 1) {
      v += __shfl_xor(v, d, 64);
      w2 += __shfl_xor(w2, d, 64);
    }
    if (ln == 0) { red2[wv][o] = v; red2[wv][o + 8] = w2; }
  }
  __syncthreads();
  float* ar = att + ((size_t)b * CC + o0) * CC;
#pragma unroll
  for (int o = 0; o < 8; o++) {
    float ssum = red2[0][o] + red2[1][o] + red2[2][o] + red2[3][o];
    float inv = 1.f / ssum;
    ar[(size_t)o * CC + t] = acc[o] * inv;
    if (t == o) {
      float bsum = red2[0][o + 8] + red2[1][o + 8] + red2[2][o + 8] + red2[3][o + 8];
      bo[b * CC + o0 + o] = bsum * inv;
    }
  }
}

// Mv[b][o][c'] = sum_d att[b][o][d] Wv[d][c']  -> bf16
__global__ __launch_bounds__(256) void nn_Mv_kernel(const float* __restrict__ att,
                                                    const float* __restrict__ Wv,
                                                    u16* __restrict__ Mvb) {
  __shared__ float As[32][33], Bs2[32][33];
  int t = threadIdx.x;
  int c0 = blockIdx.x * 32, o0 = blockIdx.y * 32, b = blockIdx.z;
  const float* Ap = att + (size_t)b * CC * CC + (size_t)o0 * CC;
  const float* Bp = Wv + c0;
  float acc[2][2] = {};
  int r = t >> 3, c4 = (t & 7) * 4;
  int tr = t >> 4, tc = t & 15;
  for (int kk = 0; kk < CC; kk += 32) {
    float4 av = *(const float4*)&Ap[(size_t)r * CC + kk + c4];
    float4 bv = *(const float4*)&Bp[(size_t)(kk + r) * CC + c4];
    As[r][c4] = av.x; As[r][c4 + 1] = av.y; As[r][c4 + 2] = av.z; As[r][c4 + 3] = av.w;
    Bs2[r][c4] = bv.x; Bs2[r][c4 + 1] = bv.y; Bs2[r][c4 + 2] = bv.z; Bs2[r][c4 + 3] = bv.w;
    __syncthreads();
#pragma unroll
    for (int k = 0; k < 32; k++) {
      float a0 = As[tr * 2][k], a1 = As[tr * 2 + 1][k];
      float b0 = Bs2[k][tc * 2], b1 = Bs2[k][tc * 2 + 1];
      acc[0][0] += a0 * b0; acc[0][1] += a0 * b1;
      acc[1][0] += a1 * b0; acc[1][1] += a1 * b1;
    }
    __syncthreads();
  }
#pragma unroll
  for (int i = 0; i < 2; i++)
#pragma unroll
    for (int j = 0; j < 2; j++)
      Mvb[(size_t)b * CC * CC + (size_t)(o0 + tr * 2 + i) * CC + c0 + tc * 2 + j] =
          f2bf(acc[i][j]);
}

// out[b][c][n] = sum_c' Mv[c][c'] x[c'][n] + bo[c] + x[c][n]
// 512-thread blocks, 128(c) x 256(n) tile, BK=64 via two 32-panels
__global__ __launch_bounds__(512) void out_kernel(const u16* __restrict__ Mvb,
                                                  const u16* __restrict__ xbT,
                                                  const float* __restrict__ bo,
                                                  const float* __restrict__ x,
                                                  float* __restrict__ out) {
  __shared__ u16 As[2][128 * 32], Bs[2][256 * 32];
  int tid = threadIdx.x;
  int n0 = blockIdx.x * 256, m0 = blockIdx.y * 128, bz = blockIdx.z;
  const u16* A = Mvb + (size_t)bz * CC * CC + (size_t)m0 * CC;
  const u16* Bt = xbT + ((size_t)bz * NN + n0) * CC;
  f32x4 acc[4][4] = {};
  int wave = tid >> 6, lane = tid & 63;
  int mb = (wave & 1) * 64, nb = (wave >> 1) * 64;
  int quad = lane >> 4, l16 = lane & 15, q8 = quad * 8;
  for (int kk = 0; kk < CC; kk += 64) {
    stage128x32_w8(A + kk, CC, As[0], tid);
    stage128x32_w8(A + kk + 32, CC, As[1], tid);
    stage256x32_w8(Bt + kk, CC, Bs[0], tid);
    stage256x32_w8(Bt + kk + 32, CC, Bs[1], tid);
    __syncthreads();
    mfma_tile(As[0], Bs[0], mb, nb, l16, q8, acc);
    mfma_tile(As[1], Bs[1], mb, nb, l16, q8, acc);
    __syncthreads();
  }
#pragma unroll
  for (int i = 0; i < 4; i++)
#pragma unroll
    for (int r = 0; r < 4; r++) {
      int cg = m0 + mb + i * 16 + quad * 4 + r;
      float bc = bo[bz * CC + cg];
#pragma unroll
      for (int j = 0; j < 4; j++) {
        int ng = n0 + nb + j * 16 + l16;
        size_t idx = ((size_t)bz * CC + cg) * NN + ng;
        out[idx] = acc[i][j][r] + bc + x[idx];
      }
    }
}

extern "C" void kernel_launch(void* const* d_in, const int* in_sizes, int n_in,
                              void* d_out, int out_size, void* d_ws, size_t ws_size,
                              hipStream_t stream) {
  (void)in_sizes; (void)n_in; (void)out_size; (void)ws_size;
  const float* x = (const float*)d_in[0];
  const float* wq = (const float*)d_in[1];
  const float* bq = (const float*)d_in[2];
  const float* wk = (const float*)d_in[3];
  const float* bk = (const float*)d_in[4];
  const float* wv = (const float*)d_in[5];
  const float* bv = (const float*)d_in[6];
  float* out = (float*)d_out;

  char* ws = (char*)d_ws;
  u16* xb    = (u16*)(ws + 0);           // 32 MiB  (B,C,N) bf16
  u16* xbT   = (u16*)(ws + 33554432);    // 32 MiB  (B,N,C) bf16
  float* G   = (float*)(ws + 67108864);  // 1 MiB   (B,C,C) fp32
  float* s   = (float*)(ws + 68157440);  // 4 KiB   (B,C)   (adjacent to G: one memset)
  float* R   = (float*)(ws + 68161536);  // 1 MiB
  float* att = (float*)(ws + 69210112);  // 1 MiB
  u16* Mvb   = (u16*)(ws + 70258688);    // 512 KiB
  float* bo  = (float*)(ws + 70782976);  // 4 KiB

  hipMemsetAsync(G, 0, 1048576 + 4096, stream);
  prep_kernel<<<dim3(NN / 64, CC / 64, BB), 256, 0, stream>>>(x, xb, xbT, s);
  gram_kernel<<<dim3(4, 32, BB), 256, 0, stream>>>(xb, G);
  ru_kernel<<<dim3(8, 8, BB), 256, 0, stream>>>(wq, G, s, bq, R);
  esb_kernel<<<dim3(32, BB), 256, 0, stream>>>(R, wq, wk, s, bq, bk, bv, att, bo);
  nn_Mv_kernel<<<dim3(8, 8, BB), 256, 0, stream>>>(att, wv, Mvb);
  out_kernel<<<dim3(NN / 256, CC / 128, BB), 512, 0, stream>>>(Mvb, xbT, bo, x, out);
}

// Round 5
// 237.204 us; speedup vs baseline: 1.2245x; 1.0433x over previous
//
#include <hip/hip_runtime.h>
#include <stdint.h>

#define BB 4
#define CC 256
#define NN 16384  // 128*128
#define NSL 32    // gram split-K slices

typedef unsigned short u16;
typedef __attribute__((ext_vector_type(8))) __bf16 bf16x8;
typedef __attribute__((ext_vector_type(4))) float f32x4;

// fp32 -> bf16 round-to-nearest-even
__device__ __forceinline__ u16 f2bf(float f) {
  union { float f; uint32_t u; } c;
  c.f = f;
  uint32_t u = c.u;
  return (u16)((u + 0x7fffu + ((u >> 16) & 1u)) >> 16);
}

// async global->LDS, 16 bytes per lane (global_load_lds_dwordx4)
__device__ __forceinline__ void g2l16(const u16* g, u16* l) {
  __builtin_amdgcn_global_load_lds((__attribute__((address_space(1))) void*)g,
                                   (__attribute__((address_space(3))) void*)l, 16, 0, 0);
}

// 256-thread block: stage 128x32 bf16 panel (row stride `stride`) into lds[128*32]
__device__ __forceinline__ void stage128x32(const u16* src, int stride, u16* lds, int tid) {
  int r = tid >> 2;
  int c = (tid & 3) << 3;
  g2l16(src + (size_t)r * stride + c, lds + r * 32 + c);
  g2l16(src + (size_t)(r + 64) * stride + c, lds + (r + 64) * 32 + c);
}

// 512-thread block: stage 128x32 panel (one g2l16/thread)
__device__ __forceinline__ void stage128x32_w8(const u16* src, int stride, u16* lds, int tid) {
  int r = tid >> 2;
  int c = (tid & 3) << 3;
  g2l16(src + (size_t)r * stride + c, lds + r * 32 + c);
}

// 512-thread block: stage 256x32 panel
__device__ __forceinline__ void stage256x32_w8(const u16* src, int stride, u16* lds, int tid) {
  int r = tid >> 2;
  int c = (tid & 3) << 3;
  g2l16(src + (size_t)r * stride + c, lds + r * 32 + c);
  g2l16(src + (size_t)(r + 128) * stride + c, lds + (r + 128) * 32 + c);
}

// one 32-deep k-step: 16 MFMAs on a 64x64 per-wave tile
__device__ __forceinline__ void mfma_tile(const u16* As, const u16* Bs, int mb, int nb,
                                          int l16, int q8, f32x4 acc[4][4]) {
  bf16x8 af[4], bf[4];
#pragma unroll
  for (int i = 0; i < 4; i++) af[i] = *(const bf16x8*)&As[(mb + i * 16 + l16) * 32 + q8];
#pragma unroll
  for (int i = 0; i < 4; i++) bf[i] = *(const bf16x8*)&Bs[(nb + i * 16 + l16) * 32 + q8];
#pragma unroll
  for (int i = 0; i < 4; i++)
#pragma unroll
    for (int j = 0; j < 4; j++)
      acc[i][j] = __builtin_amdgcn_mfma_f32_16x16x32_bf16(af[i], bf[j], acc[i][j], 0, 0, 0);
}

// prep: x fp32 (B,C,N) -> xb bf16 (B,C,N), xbT bf16 (B,N,C),
// s_part[b][ntile][c] = partial row sums (no atomics, no memset needed)
__global__ __launch_bounds__(256) void prep_kernel(const float* __restrict__ x,
                                                   u16* __restrict__ xb,
                                                   u16* __restrict__ xbT,
                                                   float* __restrict__ s_part) {
  __shared__ float t[64][65];
  __shared__ float rs[64][4];
  int n0 = blockIdx.x * 64, c0 = blockIdx.y * 64, bz = blockIdx.z;
  int tid = threadIdx.x;
  int rr0 = tid >> 4, q4 = (tid & 15) * 4;
  const float* xs = x + ((size_t)bz * CC + c0) * NN + n0;
  u16* xbp = xb + ((size_t)bz * CC + c0) * NN + n0;
#pragma unroll
  for (int cc = rr0; cc < 64; cc += 16) {
    float4 v = *(const float4*)&xs[(size_t)cc * NN + q4];
    t[cc][q4] = v.x; t[cc][q4 + 1] = v.y; t[cc][q4 + 2] = v.z; t[cc][q4 + 3] = v.w;
    union { u16 h[4]; uint2 u; } pk;
    pk.h[0] = f2bf(v.x); pk.h[1] = f2bf(v.y); pk.h[2] = f2bf(v.z); pk.h[3] = f2bf(v.w);
    *(uint2*)&xbp[(size_t)cc * NN + q4] = pk.u;
  }
  __syncthreads();
  {
    int r = tid >> 2, q = tid & 3;
    float p = 0.f;
#pragma unroll
    for (int i = 0; i < 16; i++) p += t[r][q * 16 + i];
    rs[r][q] = p;
  }
  u16* od = xbT + ((size_t)bz * NN + n0) * CC + c0;
#pragma unroll
  for (int nn = rr0; nn < 64; nn += 16) {
    union { u16 h[4]; uint2 u; } pk;
    pk.h[0] = f2bf(t[q4][nn]); pk.h[1] = f2bf(t[q4 + 1][nn]);
    pk.h[2] = f2bf(t[q4 + 2][nn]); pk.h[3] = f2bf(t[q4 + 3][nn]);
    *(uint2*)&od[(size_t)nn * CC + q4] = pk.u;
  }
  __syncthreads();
  if (tid < 64)
    s_part[((size_t)bz * 256 + blockIdx.x) * CC + c0 + tid] =
        rs[tid][0] + rs[tid][1] + rs[tid][2] + rs[tid][3];
}

// Gp[sl][b] = partial xb xb^T over K-slice sl (plain stores, NO atomics)
__global__ __launch_bounds__(256) void gram_kernel(const u16* __restrict__ xb,
                                                   float* __restrict__ Gp) {
  __shared__ u16 As[2][128 * 32], Bs[2][128 * 32];
  int tid = threadIdx.x;
  int c0 = (blockIdx.x >> 1) * 128, d0 = (blockIdx.x & 1) * 128;
  int sl = blockIdx.y, bz = blockIdx.z;
  const u16* A = xb + ((size_t)bz * CC + c0) * NN + sl * 512;
  const u16* Bt = xb + ((size_t)bz * CC + d0) * NN + sl * 512;
  f32x4 acc[4][4] = {};
  int wave = tid >> 6, lane = tid & 63;
  int mb = (wave >> 1) * 64, nb = (wave & 1) * 64;
  int quad = lane >> 4, l16 = lane & 15, q8 = quad * 8;
  for (int kk = 0; kk < 512; kk += 64) {
    stage128x32(A + kk, NN, As[0], tid);
    stage128x32(A + kk + 32, NN, As[1], tid);
    stage128x32(Bt + kk, NN, Bs[0], tid);
    stage128x32(Bt + kk + 32, NN, Bs[1], tid);
    __syncthreads();
    mfma_tile(As[0], Bs[0], mb, nb, l16, q8, acc);
    mfma_tile(As[1], Bs[1], mb, nb, l16, q8, acc);
    __syncthreads();
  }
  float* gp = Gp + ((size_t)sl * BB + bz) * CC * CC;
#pragma unroll
  for (int i = 0; i < 4; i++)
#pragma unroll
    for (int j = 0; j < 4; j++)
#pragma unroll
      for (int r = 0; r < 4; r++)
        gp[(size_t)(c0 + mb + i * 16 + quad * 4 + r) * CC + d0 + nb + j * 16 + l16] =
            acc[i][j][r];
}

// reduce: G = sum_sl Gp[sl]; s = sum_nt s_part
__global__ __launch_bounds__(256) void reduce_kernel(const float* __restrict__ Gp,
                                                     const float* __restrict__ s_part,
                                                     float* __restrict__ G,
                                                     float* __restrict__ s) {
  int t = threadIdx.x, blk = blockIdx.x;
  size_t base = ((size_t)blk * 256 + t) * 4;
  float ax = 0.f, ay = 0.f, az = 0.f, aw = 0.f;
#pragma unroll 8
  for (int sl = 0; sl < NSL; sl++) {
    float4 v = *(const float4*)&Gp[(size_t)sl * (BB * CC * CC) + base];
    ax += v.x; ay += v.y; az += v.z; aw += v.w;
  }
  float4 o; o.x = ax; o.y = ay; o.z = az; o.w = aw;
  *(float4*)&G[base] = o;
  if (blk < BB) {
    float a = 0.f;
#pragma unroll 8
    for (int nt = 0; nt < 256; nt++) a += s_part[((size_t)blk * 256 + nt) * CC + t];
    s[blk * CC + t] = a;
  }
}

// mid: per block (2 o-rows, b): R = Wq G + bq (x) s ; E = R Wk^T + u' (x) bk ;
// softmax ; Mv = att Wv (bf16 out) ; bo = att . bv.  att never hits HBM.
__global__ __launch_bounds__(256) void mid_kernel(
    const float* __restrict__ G, const float* __restrict__ s,
    const float* __restrict__ Wq, const float* __restrict__ Wk,
    const float* __restrict__ Wv,
    const float* __restrict__ bq, const float* __restrict__ bk,
    const float* __restrict__ bv,
    u16* __restrict__ Mvb, float* __restrict__ bo) {
  __shared__ float sS[CC];
  __shared__ float rS[2][CC];
  __shared__ float attS[2][CC];
  __shared__ float redA[2][4], redB[2][4], redC[2][4], redD[2][4];
  int t = threadIdx.x;
  int o0 = blockIdx.x * 2, b = blockIdx.y;
  int wv = t >> 6, ln = t & 63;
  sS[t] = s[b * CC + t];
  __syncthreads();
  // u'[i] = Wq[o0+i,:].s + N*bq
  float p0 = Wq[(size_t)o0 * CC + t] * sS[t];
  float p1 = Wq[(size_t)(o0 + 1) * CC + t] * sS[t];
#pragma unroll
  for (int d = 32; d > 0; d >>= 1) {
    p0 += __shfl_xor(p0, d, 64);
    p1 += __shfl_xor(p1, d, 64);
  }
  if (ln == 0) { redA[0][wv] = p0; redA[1][wv] = p1; }
  __syncthreads();
  float up0 = redA[0][0] + redA[0][1] + redA[0][2] + redA[0][3] + 16384.f * bq[o0];
  float up1 = redA[1][0] + redA[1][1] + redA[1][2] + redA[1][3] + 16384.f * bq[o0 + 1];
  // R rows (thread = c). Wq reads are block-uniform -> scalar loads.
  const float* Gb = G + (size_t)b * CC * CC;
  const float* wq0 = Wq + (size_t)o0 * CC;
  const float* wq1 = wq0 + CC;
  float r0 = bq[o0] * sS[t], r1 = bq[o0 + 1] * sS[t];
#pragma unroll 8
  for (int d = 0; d < CC; d++) {
    float g = Gb[d * CC + t];
    r0 += wq0[d] * g;
    r1 += wq1[d] * g;
  }
  rS[0][t] = r0;
  rS[1][t] = r1;
  __syncthreads();
  // E rows (thread = p)
  float e0 = up0 * bk[t], e1 = up1 * bk[t];
  const float* wkr = Wk + (size_t)t * CC;
#pragma unroll 4
  for (int c = 0; c < CC; c += 4) {
    float4 w4 = *(const float4*)&wkr[c];
    float4 ra = *(const float4*)&rS[0][c];
    float4 rb = *(const float4*)&rS[1][c];
    e0 += ra.x * w4.x + ra.y * w4.y + ra.z * w4.z + ra.w * w4.w;
    e1 += rb.x * w4.x + rb.y * w4.y + rb.z * w4.z + rb.w * w4.w;
  }
  e0 *= 0.0078125f;
  e1 *= 0.0078125f;
  // softmax over 256 p
  float m0 = e0, m1 = e1;
#pragma unroll
  for (int d = 32; d > 0; d >>= 1) {
    m0 = fmaxf(m0, __shfl_xor(m0, d, 64));
    m1 = fmaxf(m1, __shfl_xor(m1, d, 64));
  }
  if (ln == 0) { redB[0][wv] = m0; redB[1][wv] = m1; }
  __syncthreads();
  m0 = fmaxf(fmaxf(redB[0][0], redB[0][1]), fmaxf(redB[0][2], redB[0][3]));
  m1 = fmaxf(fmaxf(redB[1][0], redB[1][1]), fmaxf(redB[1][2], redB[1][3]));
  e0 = __expf(e0 - m0);
  e1 = __expf(e1 - m1);
  float s0 = e0, s1 = e1;
#pragma unroll
  for (int d = 32; d > 0; d >>= 1) {
    s0 += __shfl_xor(s0, d, 64);
    s1 += __shfl_xor(s1, d, 64);
  }
  if (ln == 0) { redC[0][wv] = s0; redC[1][wv] = s1; }
  __syncthreads();
  float inv0 = 1.f / (redC[0][0] + redC[0][1] + redC[0][2] + redC[0][3]);
  float inv1 = 1.f / (redC[1][0] + redC[1][1] + redC[1][2] + redC[1][3]);
  float a0 = e0 * inv0, a1 = e1 * inv1;
  attS[0][t] = a0;
  attS[1][t] = a1;
  // bo
  float b0 = a0 * bv[t], b1 = a1 * bv[t];
#pragma unroll
  for (int d = 32; d > 0; d >>= 1) {
    b0 += __shfl_xor(b0, d, 64);
    b1 += __shfl_xor(b1, d, 64);
  }
  if (ln == 0) { redD[0][wv] = b0; redD[1][wv] = b1; }
  __syncthreads();
  if (t == 0) bo[b * CC + o0] = redD[0][0] + redD[0][1] + redD[0][2] + redD[0][3];
  if (t == 1) bo[b * CC + o0 + 1] = redD[1][0] + redD[1][1] + redD[1][2] + redD[1][3];
  // Mv rows (thread = c'); attS reads are uniform -> LDS broadcast
  float mv0 = 0.f, mv1 = 0.f;
#pragma unroll 8
  for (int d = 0; d < CC; d++) {
    float w = Wv[d * CC + t];
    mv0 += attS[0][d] * w;
    mv1 += attS[1][d] * w;
  }
  Mvb[((size_t)b * CC + o0) * CC + t] = f2bf(mv0);
  Mvb[((size_t)b * CC + o0 + 1) * CC + t] = f2bf(mv1);
}

// out[b][c][n] = sum_c' Mv[c][c'] x[c'][n] + bo[c] + x[c][n]
// 512-thread blocks, 128(c) x 256(n) tile, BK=64 via two 32-panels
__global__ __launch_bounds__(512) void out_kernel(const u16* __restrict__ Mvb,
                                                  const u16* __restrict__ xbT,
                                                  const float* __restrict__ bo,
                                                  const float* __restrict__ x,
                                                  float* __restrict__ out) {
  __shared__ u16 As[2][128 * 32], Bs[2][256 * 32];
  int tid = threadIdx.x;
  int n0 = blockIdx.x * 256, m0 = blockIdx.y * 128, bz = blockIdx.z;
  const u16* A = Mvb + (size_t)bz * CC * CC + (size_t)m0 * CC;
  const u16* Bt = xbT + ((size_t)bz * NN + n0) * CC;
  f32x4 acc[4][4] = {};
  int wave = tid >> 6, lane = tid & 63;
  int mb = (wave & 1) * 64, nb = (wave >> 1) * 64;
  int quad = lane >> 4, l16 = lane & 15, q8 = quad * 8;
  for (int kk = 0; kk < CC; kk += 64) {
    stage128x32_w8(A + kk, CC, As[0], tid);
    stage128x32_w8(A + kk + 32, CC, As[1], tid);
    stage256x32_w8(Bt + kk, CC, Bs[0], tid);
    stage256x32_w8(Bt + kk + 32, CC, Bs[1], tid);
    __syncthreads();
    mfma_tile(As[0], Bs[0], mb, nb, l16, q8, acc);
    mfma_tile(As[1], Bs[1], mb, nb, l16, q8, acc);
    __syncthreads();
  }
#pragma unroll
  for (int i = 0; i < 4; i++)
#pragma unroll
    for (int r = 0; r < 4; r++) {
      int cg = m0 + mb + i * 16 + quad * 4 + r;
      float bc = bo[bz * CC + cg];
#pragma unroll
      for (int j = 0; j < 4; j++) {
        int ng = n0 + nb + j * 16 + l16;
        size_t idx = ((size_t)bz * CC + cg) * NN + ng;
        out[idx] = acc[i][j][r] + bc + x[idx];
      }
    }
}

extern "C" void kernel_launch(void* const* d_in, const int* in_sizes, int n_in,
                              void* d_out, int out_size, void* d_ws, size_t ws_size,
                              hipStream_t stream) {
  (void)in_sizes; (void)n_in; (void)out_size; (void)ws_size;
  const float* x = (const float*)d_in[0];
  const float* wq = (const float*)d_in[1];
  const float* bq = (const float*)d_in[2];
  const float* wk = (const float*)d_in[3];
  const float* bk = (const float*)d_in[4];
  const float* wv = (const float*)d_in[5];
  const float* bv = (const float*)d_in[6];
  float* out = (float*)d_out;

  char* ws = (char*)d_ws;
  u16* xb      = (u16*)(ws + 0);            // 32 MiB  (B,C,N) bf16
  u16* xbT     = (u16*)(ws + 33554432);     // 32 MiB  (B,N,C) bf16
  float* Gp    = (float*)(ws + 67108864);   // 32 MiB  (NSL,B,C,C) fp32 partials
  float* G     = (float*)(ws + 100663296);  // 1 MiB
  float* s_prt = (float*)(ws + 101711872);  // 1 MiB   (B,256,C)
  float* s     = (float*)(ws + 102760448);  // 4 KiB
  u16* Mvb     = (u16*)(ws + 102764544);    // 512 KiB
  float* bo    = (float*)(ws + 103288832);  // 4 KiB

  prep_kernel<<<dim3(NN / 64, CC / 64, BB), 256, 0, stream>>>(x, xb, xbT, s_prt);
  gram_kernel<<<dim3(4, NSL, BB), 256, 0, stream>>>(xb, Gp);
  reduce_kernel<<<256, 256, 0, stream>>>(Gp, s_prt, G, s);
  mid_kernel<<<dim3(CC / 2, BB), 256, 0, stream>>>(G, s, wq, wk, wv, bq, bk, bv, Mvb, bo);
  out_kernel<<<dim3(NN / 256, CC / 128, BB), 512, 0, stream>>>(Mvb, xbT, bo, x, out);
}

// Round 6
// 231.650 us; speedup vs baseline: 1.2539x; 1.0240x over previous
//
#include <hip/hip_runtime.h>
#include <stdint.h>

#define BB 4
#define CC 256
#define NN 16384  // 128*128
#define NSL 32    // gram split-K slices

typedef unsigned short u16;
typedef __attribute__((ext_vector_type(8))) __bf16 bf16x8;
typedef __attribute__((ext_vector_type(4))) float f32x4;

// fp32 -> bf16 round-to-nearest-even
__device__ __forceinline__ u16 f2bf(float f) {
  union { float f; uint32_t u; } c;
  c.f = f;
  uint32_t u = c.u;
  return (u16)((u + 0x7fffu + ((u >> 16) & 1u)) >> 16);
}

// async global->LDS, 16 bytes per lane (global_load_lds_dwordx4)
__device__ __forceinline__ void g2l16(const u16* g, u16* l) {
  __builtin_amdgcn_global_load_lds((__attribute__((address_space(1))) void*)g,
                                   (__attribute__((address_space(3))) void*)l, 16, 0, 0);
}

// 256-thread block: stage 128x32 bf16 panel (row stride `stride`) into lds[128*32]
__device__ __forceinline__ void stage128x32(const u16* src, int stride, u16* lds, int tid) {
  int r = tid >> 2;
  int c = (tid & 3) << 3;
  g2l16(src + (size_t)r * stride + c, lds + r * 32 + c);
  g2l16(src + (size_t)(r + 64) * stride + c, lds + (r + 64) * 32 + c);
}

// 512-thread block: stage 128x32 panel (one g2l16/thread)
__device__ __forceinline__ void stage128x32_w8(const u16* src, int stride, u16* lds, int tid) {
  int r = tid >> 2;
  int c = (tid & 3) << 3;
  g2l16(src + (size_t)r * stride + c, lds + r * 32 + c);
}

// 512-thread block: stage 256x32 panel
__device__ __forceinline__ void stage256x32_w8(const u16* src, int stride, u16* lds, int tid) {
  int r = tid >> 2;
  int c = (tid & 3) << 3;
  g2l16(src + (size_t)r * stride + c, lds + r * 32 + c);
  g2l16(src + (size_t)(r + 128) * stride + c, lds + (r + 128) * 32 + c);
}

// one 32-deep k-step: 16 MFMAs on a 64x64 per-wave tile
__device__ __forceinline__ void mfma_tile(const u16* As, const u16* Bs, int mb, int nb,
                                          int l16, int q8, f32x4 acc[4][4]) {
  bf16x8 af[4], bf[4];
#pragma unroll
  for (int i = 0; i < 4; i++) af[i] = *(const bf16x8*)&As[(mb + i * 16 + l16) * 32 + q8];
#pragma unroll
  for (int i = 0; i < 4; i++) bf[i] = *(const bf16x8*)&Bs[(nb + i * 16 + l16) * 32 + q8];
#pragma unroll
  for (int i = 0; i < 4; i++)
#pragma unroll
    for (int j = 0; j < 4; j++)
      acc[i][j] = __builtin_amdgcn_mfma_f32_16x16x32_bf16(af[i], bf[j], acc[i][j], 0, 0, 0);
}

// prep: x fp32 (B,C,N) -> xb bf16 (B,C,N), xbT bf16 (B,N,C),
// s_part[b][ntile][c] = partial row sums (no atomics, no memset needed)
__global__ __launch_bounds__(256) void prep_kernel(const float* __restrict__ x,
                                                   u16* __restrict__ xb,
                                                   u16* __restrict__ xbT,
                                                   float* __restrict__ s_part) {
  __shared__ float t[64][65];
  __shared__ float rs[64][4];
  int n0 = blockIdx.x * 64, c0 = blockIdx.y * 64, bz = blockIdx.z;
  int tid = threadIdx.x;
  int rr0 = tid >> 4, q4 = (tid & 15) * 4;
  const float* xs = x + ((size_t)bz * CC + c0) * NN + n0;
  u16* xbp = xb + ((size_t)bz * CC + c0) * NN + n0;
#pragma unroll
  for (int cc = rr0; cc < 64; cc += 16) {
    float4 v = *(const float4*)&xs[(size_t)cc * NN + q4];
    t[cc][q4] = v.x; t[cc][q4 + 1] = v.y; t[cc][q4 + 2] = v.z; t[cc][q4 + 3] = v.w;
    union { u16 h[4]; uint2 u; } pk;
    pk.h[0] = f2bf(v.x); pk.h[1] = f2bf(v.y); pk.h[2] = f2bf(v.z); pk.h[3] = f2bf(v.w);
    *(uint2*)&xbp[(size_t)cc * NN + q4] = pk.u;
  }
  __syncthreads();
  {
    int r = tid >> 2, q = tid & 3;
    float p = 0.f;
#pragma unroll
    for (int i = 0; i < 16; i++) p += t[r][q * 16 + i];
    rs[r][q] = p;
  }
  u16* od = xbT + ((size_t)bz * NN + n0) * CC + c0;
#pragma unroll
  for (int nn = rr0; nn < 64; nn += 16) {
    union { u16 h[4]; uint2 u; } pk;
    pk.h[0] = f2bf(t[q4][nn]); pk.h[1] = f2bf(t[q4 + 1][nn]);
    pk.h[2] = f2bf(t[q4 + 2][nn]); pk.h[3] = f2bf(t[q4 + 3][nn]);
    *(uint2*)&od[(size_t)nn * CC + q4] = pk.u;
  }
  __syncthreads();
  if (tid < 64)
    s_part[((size_t)bz * 256 + blockIdx.x) * CC + c0 + tid] =
        rs[tid][0] + rs[tid][1] + rs[tid][2] + rs[tid][3];
}

// Gp[sl][b] = partial xb xb^T over K-slice sl (plain stores, NO atomics)
__global__ __launch_bounds__(256) void gram_kernel(const u16* __restrict__ xb,
                                                   float* __restrict__ Gp) {
  __shared__ u16 As[2][128 * 32], Bs[2][128 * 32];
  int tid = threadIdx.x;
  int c0 = (blockIdx.x >> 1) * 128, d0 = (blockIdx.x & 1) * 128;
  int sl = blockIdx.y, bz = blockIdx.z;
  const u16* A = xb + ((size_t)bz * CC + c0) * NN + sl * 512;
  const u16* Bt = xb + ((size_t)bz * CC + d0) * NN + sl * 512;
  f32x4 acc[4][4] = {};
  int wave = tid >> 6, lane = tid & 63;
  int mb = (wave >> 1) * 64, nb = (wave & 1) * 64;
  int quad = lane >> 4, l16 = lane & 15, q8 = quad * 8;
  for (int kk = 0; kk < 512; kk += 64) {
    stage128x32(A + kk, NN, As[0], tid);
    stage128x32(A + kk + 32, NN, As[1], tid);
    stage128x32(Bt + kk, NN, Bs[0], tid);
    stage128x32(Bt + kk + 32, NN, Bs[1], tid);
    __syncthreads();
    mfma_tile(As[0], Bs[0], mb, nb, l16, q8, acc);
    mfma_tile(As[1], Bs[1], mb, nb, l16, q8, acc);
    __syncthreads();
  }
  float* gp = Gp + ((size_t)sl * BB + bz) * CC * CC;
#pragma unroll
  for (int i = 0; i < 4; i++)
#pragma unroll
    for (int j = 0; j < 4; j++)
#pragma unroll
      for (int r = 0; r < 4; r++)
        gp[(size_t)(c0 + mb + i * 16 + quad * 4 + r) * CC + d0 + nb + j * 16 + l16] =
            acc[i][j][r];
}

// reduce: G = sum_sl Gp[sl]; s = sum_nt s_part; blocks 0..63 also build WkT
__global__ __launch_bounds__(256) void reduce_kernel(const float* __restrict__ Gp,
                                                     const float* __restrict__ s_part,
                                                     const float* __restrict__ Wk,
                                                     float* __restrict__ G,
                                                     float* __restrict__ s,
                                                     float* __restrict__ WkT) {
  __shared__ float tw[32][33];
  int t = threadIdx.x, blk = blockIdx.x;
  size_t base = ((size_t)blk * 256 + t) * 4;
  float ax = 0.f, ay = 0.f, az = 0.f, aw = 0.f;
#pragma unroll 8
  for (int sl = 0; sl < NSL; sl++) {
    float4 v = *(const float4*)&Gp[(size_t)sl * (BB * CC * CC) + base];
    ax += v.x; ay += v.y; az += v.z; aw += v.w;
  }
  float4 o; o.x = ax; o.y = ay; o.z = az; o.w = aw;
  *(float4*)&G[base] = o;
  if (blk < BB) {
    float a = 0.f;
#pragma unroll 8
    for (int nt = 0; nt < 256; nt++) a += s_part[((size_t)blk * 256 + nt) * CC + t];
    s[blk * CC + t] = a;
  }
  // Wk transpose: 64 blocks handle the 8x8 grid of 32x32 tiles
  if (blk < 64) {
    int tr = blk >> 3, tc = blk & 7;
    int r = t >> 5, c = t & 31;
#pragma unroll
    for (int i = 0; i < 4; i++)
      tw[r + i * 8][c] = Wk[(size_t)(tr * 32 + r + i * 8) * CC + tc * 32 + c];
    __syncthreads();
#pragma unroll
    for (int i = 0; i < 4; i++)
      WkT[(size_t)(tc * 32 + r + i * 8) * CC + tr * 32 + c] = tw[c][r + i * 8];
  }
}

// mid: per block (2 o-rows, b): R = Wq G + bq (x) s ; E = R WkT + u' (x) bk ;
// softmax ; Mv = att Wv (bf16 out) ; bo = att . bv.  att never hits HBM.
// All global loads in the hot loops are coalesced column-reads (lane = col).
__global__ __launch_bounds__(256) void mid_kernel(
    const float* __restrict__ G, const float* __restrict__ s,
    const float* __restrict__ Wq, const float* __restrict__ WkT,
    const float* __restrict__ Wv,
    const float* __restrict__ bq, const float* __restrict__ bk,
    const float* __restrict__ bv,
    u16* __restrict__ Mvb, float* __restrict__ bo) {
  __shared__ float sS[CC];
  __shared__ float rS[2][CC];
  __shared__ float attS[2][CC];
  __shared__ float redA[2][4], redB[2][4], redC[2][4], redD[2][4];
  int t = threadIdx.x;
  int o0 = blockIdx.x * 2, b = blockIdx.y;
  int wv = t >> 6, ln = t & 63;
  sS[t] = s[b * CC + t];
  __syncthreads();
  // u'[i] = Wq[o0+i,:].s + N*bq
  float p0 = Wq[(size_t)o0 * CC + t] * sS[t];
  float p1 = Wq[(size_t)(o0 + 1) * CC + t] * sS[t];
#pragma unroll
  for (int d = 32; d > 0; d >>= 1) {
    p0 += __shfl_xor(p0, d, 64);
    p1 += __shfl_xor(p1, d, 64);
  }
  if (ln == 0) { redA[0][wv] = p0; redA[1][wv] = p1; }
  __syncthreads();
  float up0 = redA[0][0] + redA[0][1] + redA[0][2] + redA[0][3] + 16384.f * bq[o0];
  float up1 = redA[1][0] + redA[1][1] + redA[1][2] + redA[1][3] + 16384.f * bq[o0 + 1];
  // R rows (thread = c). Wq reads are block-uniform -> scalar loads.
  const float* Gb = G + (size_t)b * CC * CC;
  const float* wq0 = Wq + (size_t)o0 * CC;
  const float* wq1 = wq0 + CC;
  float r0 = bq[o0] * sS[t], r1 = bq[o0 + 1] * sS[t];
#pragma unroll 8
  for (int d = 0; d < CC; d++) {
    float g = Gb[d * CC + t];
    r0 += wq0[d] * g;
    r1 += wq1[d] * g;
  }
  rS[0][t] = r0;
  rS[1][t] = r1;
  __syncthreads();
  // E rows (thread = p): coalesced WkT column reads + LDS broadcast of rS
  float e0 = up0 * bk[t], e1 = up1 * bk[t];
#pragma unroll 8
  for (int c = 0; c < CC; c++) {
    float w = WkT[(size_t)c * CC + t];
    e0 += rS[0][c] * w;
    e1 += rS[1][c] * w;
  }
  e0 *= 0.0078125f;
  e1 *= 0.0078125f;
  // softmax over 256 p
  float m0 = e0, m1 = e1;
#pragma unroll
  for (int d = 32; d > 0; d >>= 1) {
    m0 = fmaxf(m0, __shfl_xor(m0, d, 64));
    m1 = fmaxf(m1, __shfl_xor(m1, d, 64));
  }
  if (ln == 0) { redB[0][wv] = m0; redB[1][wv] = m1; }
  __syncthreads();
  m0 = fmaxf(fmaxf(redB[0][0], redB[0][1]), fmaxf(redB[0][2], redB[0][3]));
  m1 = fmaxf(fmaxf(redB[1][0], redB[1][1]), fmaxf(redB[1][2], redB[1][3]));
  e0 = __expf(e0 - m0);
  e1 = __expf(e1 - m1);
  float s0 = e0, s1 = e1;
#pragma unroll
  for (int d = 32; d > 0; d >>= 1) {
    s0 += __shfl_xor(s0, d, 64);
    s1 += __shfl_xor(s1, d, 64);
  }
  if (ln == 0) { redC[0][wv] = s0; redC[1][wv] = s1; }
  __syncthreads();
  float inv0 = 1.f / (redC[0][0] + redC[0][1] + redC[0][2] + redC[0][3]);
  float inv1 = 1.f / (redC[1][0] + redC[1][1] + redC[1][2] + redC[1][3]);
  float a0 = e0 * inv0, a1 = e1 * inv1;
  attS[0][t] = a0;
  attS[1][t] = a1;
  // bo
  float b0 = a0 * bv[t], b1 = a1 * bv[t];
#pragma unroll
  for (int d = 32; d > 0; d >>= 1) {
    b0 += __shfl_xor(b0, d, 64);
    b1 += __shfl_xor(b1, d, 64);
  }
  if (ln == 0) { redD[0][wv] = b0; redD[1][wv] = b1; }
  __syncthreads();
  if (t == 0) bo[b * CC + o0] = redD[0][0] + redD[0][1] + redD[0][2] + redD[0][3];
  if (t == 1) bo[b * CC + o0 + 1] = redD[1][0] + redD[1][1] + redD[1][2] + redD[1][3];
  // Mv rows (thread = c'); attS reads are uniform -> LDS broadcast
  float mv0 = 0.f, mv1 = 0.f;
#pragma unroll 8
  for (int d = 0; d < CC; d++) {
    float w = Wv[d * CC + t];
    mv0 += attS[0][d] * w;
    mv1 += attS[1][d] * w;
  }
  Mvb[((size_t)b * CC + o0) * CC + t] = f2bf(mv0);
  Mvb[((size_t)b * CC + o0 + 1) * CC + t] = f2bf(mv1);
}

// out[b][c][n] = sum_c' Mv[c][c'] x[c'][n] + bo[c] + x[c][n]
// 512-thread blocks, 128(c) x 256(n) tile, BK=64 via two 32-panels
__global__ __launch_bounds__(512) void out_kernel(const u16* __restrict__ Mvb,
                                                  const u16* __restrict__ xbT,
                                                  const float* __restrict__ bo,
                                                  const float* __restrict__ x,
                                                  float* __restrict__ out) {
  __shared__ u16 As[2][128 * 32], Bs[2][256 * 32];
  int tid = threadIdx.x;
  int n0 = blockIdx.x * 256, m0 = blockIdx.y * 128, bz = blockIdx.z;
  const u16* A = Mvb + (size_t)bz * CC * CC + (size_t)m0 * CC;
  const u16* Bt = xbT + ((size_t)bz * NN + n0) * CC;
  f32x4 acc[4][4] = {};
  int wave = tid >> 6, lane = tid & 63;
  int mb = (wave & 1) * 64, nb = (wave >> 1) * 64;
  int quad = lane >> 4, l16 = lane & 15, q8 = quad * 8;
  for (int kk = 0; kk < CC; kk += 64) {
    stage128x32_w8(A + kk, CC, As[0], tid);
    stage128x32_w8(A + kk + 32, CC, As[1], tid);
    stage256x32_w8(Bt + kk, CC, Bs[0], tid);
    stage256x32_w8(Bt + kk + 32, CC, Bs[1], tid);
    __syncthreads();
    mfma_tile(As[0], Bs[0], mb, nb, l16, q8, acc);
    mfma_tile(As[1], Bs[1], mb, nb, l16, q8, acc);
    __syncthreads();
  }
#pragma unroll
  for (int i = 0; i < 4; i++)
#pragma unroll
    for (int r = 0; r < 4; r++) {
      int cg = m0 + mb + i * 16 + quad * 4 + r;
      float bc = bo[bz * CC + cg];
#pragma unroll
      for (int j = 0; j < 4; j++) {
        int ng = n0 + nb + j * 16 + l16;
        size_t idx = ((size_t)bz * CC + cg) * NN + ng;
        out[idx] = acc[i][j][r] + bc + x[idx];
      }
    }
}

extern "C" void kernel_launch(void* const* d_in, const int* in_sizes, int n_in,
                              void* d_out, int out_size, void* d_ws, size_t ws_size,
                              hipStream_t stream) {
  (void)in_sizes; (void)n_in; (void)out_size; (void)ws_size;
  const float* x = (const float*)d_in[0];
  const float* wq = (const float*)d_in[1];
  const float* bq = (const float*)d_in[2];
  const float* wk = (const float*)d_in[3];
  const float* bk = (const float*)d_in[4];
  const float* wv = (const float*)d_in[5];
  const float* bv = (const float*)d_in[6];
  float* out = (float*)d_out;

  char* ws = (char*)d_ws;
  u16* xb      = (u16*)(ws + 0);            // 32 MiB  (B,C,N) bf16
  u16* xbT     = (u16*)(ws + 33554432);     // 32 MiB  (B,N,C) bf16
  float* Gp    = (float*)(ws + 67108864);   // 32 MiB  (NSL,B,C,C) fp32 partials
  float* G     = (float*)(ws + 100663296);  // 1 MiB
  float* s_prt = (float*)(ws + 101711872);  // 1 MiB   (B,256,C)
  float* s     = (float*)(ws + 102760448);  // 4 KiB
  u16* Mvb     = (u16*)(ws + 102764544);    // 512 KiB
  float* bo    = (float*)(ws + 103288832);  // 4 KiB
  float* WkT   = (float*)(ws + 103292928);  // 256 KiB

  prep_kernel<<<dim3(NN / 64, CC / 64, BB), 256, 0, stream>>>(x, xb, xbT, s_prt);
  gram_kernel<<<dim3(4, NSL, BB), 256, 0, stream>>>(xb, Gp);
  reduce_kernel<<<256, 256, 0, stream>>>(Gp, s_prt, wk, G, s, WkT);
  mid_kernel<<<dim3(CC / 2, BB), 256, 0, stream>>>(G, s, wq, WkT, wv, bq, bk, bv, Mvb, bo);
  out_kernel<<<dim3(NN / 256, CC / 128, BB), 512, 0, stream>>>(Mvb, xbT, bo, x, out);
}